// Round 13
// baseline (113.813 us; speedup 1.0000x reference)
//
#include <hip/hip_runtime.h>
#include <hip/hip_bf16.h>
#include <math.h>

// Problem constants (reference: B=32, P=256, D=64, T=4096, SCALE=1)
#define Bb 32
#define Pp 256
#define Dd 64
#define Tt 4096

typedef unsigned short ushort_t;
typedef __attribute__((ext_vector_type(8))) short bf16x8;   // 8 bf16 = 4 VGPRs
typedef __attribute__((ext_vector_type(4))) float f32x4;

#define TRIP2_BYTES ((size_t)Bb * Pp * 128 * 16)  // 16,777,216 (128 strips)
#define TRIP_BYTES  ((size_t)Bb * Pp * 64 * 16)   //  8,388,608 (fallback)

// x = hi(bf16,RNE) + lo(bf16): dropped al*bl term ~2^-17 rel; pred err ~5e-4.
__device__ __forceinline__ void split8(const float* __restrict__ x,
                                       bf16x8& hi, bf16x8& lo) {
#pragma unroll
  for (int j = 0; j < 8; ++j) {
    const __hip_bfloat16 hb = __float2bfloat16(x[j]);
    const float hf = __bfloat162float(hb);
    const __hip_bfloat16 lb = __float2bfloat16(x[j] - hf);
    hi[j] = *(const short*)&hb;
    lo[j] = *(const short*)&lb;
  }
}

#define MFMA6(a)                                                     \
  a = __builtin_amdgcn_mfma_f32_16x16x32_bf16(ah0, bh0, a, 0, 0, 0); \
  a = __builtin_amdgcn_mfma_f32_16x16x32_bf16(ah1, bh1, a, 0, 0, 0); \
  a = __builtin_amdgcn_mfma_f32_16x16x32_bf16(ah0, bl0, a, 0, 0, 0); \
  a = __builtin_amdgcn_mfma_f32_16x16x32_bf16(al0, bh0, a, 0, 0, 0); \
  a = __builtin_amdgcn_mfma_f32_16x16x32_bf16(ah1, bl1, a, 0, 0, 0); \
  a = __builtin_amdgcn_mfma_f32_16x16x32_bf16(al1, bh1, a, 0, 0, 0);

// ==================== Phase 1: one-pass fused prefix-softmax ================
// R12 post-mortem: k_main was LATENCY-bound (VALUBusy 34%, 2 blocks/CU from
// 73.7KB LDS; issue arithmetic ~10us vs 47us measured). R13: strip=128t ->
// 1024 blocks x 36.9KB LDS = 4 blocks/CU = 4 waves/SIMD (2x warp pool), and
// split-bf16 conversion FUSED in-kernel (k_conv launch deleted; conversion is
// ~300 VALU inst/block, free under latency). Everything else is R12-proven:
// serial sg loop with in-register prefix, quad-exclusive prefix via 3
// shuffles, batch softmax + l16 butterfly, factored-triple stores.
// NaN-safety (R3): per-wave M is the exact max of that wave's cc -> argmax
// term contributes exp(0)=1 -> S>=1; factored exp(m-M) merges are exact.
__global__ __launch_bounds__(256, 4) void k_main2(const float* __restrict__ data,
                                                  const float* __restrict__ Wt,
                                                  const float* __restrict__ targets,
                                                  float4* __restrict__ triples) {
  __shared__ short Bhs[128 * 72];   // padded rows: 72 shorts = 144B (16B-aligned)
  __shared__ short Bls[128 * 72];
  const int tid  = threadIdx.x;
  const int wid  = tid >> 6;
  const int lane = tid & 63;
  const int quad = lane >> 4;
  const int l16  = lane & 15;
  const int b     = blockIdx.x >> 5;
  const int strip = blockIdx.x & 31;
  const int t0    = strip * 128;

  // ---- stage B-strip: read fp32 task_pool rows, split to bf16 hi/lo in LDS
  {
    const float4* src = (const float4*)(Wt + (size_t)t0 * Dd);  // 2048 float4
#pragma unroll
    for (int j = 0; j < 8; ++j) {
      const int idx = tid + j * 256;
      const int tl  = idx >> 4;            // 16 float4 per 64-float row
      const int col = (idx & 15) * 4;      // float col within row
      const float4 v = src[idx];
      const float xs[4] = {v.x, v.y, v.z, v.w};
      short h4[4], l4[4];
#pragma unroll
      for (int u = 0; u < 4; ++u) {
        const __hip_bfloat16 hb = __float2bfloat16(xs[u]);
        const float hf = __bfloat162float(hb);
        const __hip_bfloat16 lb = __float2bfloat16(xs[u] - hf);
        h4[u] = *(const short*)&hb;
        l4[u] = *(const short*)&lb;
      }
      *(short4*)&Bhs[tl * 72 + col] = make_short4(h4[0], h4[1], h4[2], h4[3]);
      *(short4*)&Bls[tl * 72 + col] = make_short4(l4[0], l4[1], l4[2], l4[3]);
    }
  }
  __syncthreads();

  const float* __restrict__ abase = data + (size_t)b * Pp * Dd;
  float4* __restrict__ trb = triples + (size_t)b * Pp * 128;
  const int wstrip = strip * 4 + wid;      // 0..127 (this wave's t-subset id)

  float R[2];                              // per-column running prefix
  R[0] = 0.f; R[1] = 0.f;

#pragma unroll 1
  for (int sg = 0; sg < 16; ++sg) {
    const int p0 = sg * 16;
    // A fragments: load fp32 row (p0+l16), split on the fly (L1-shared by waves)
    bf16x8 ah0, al0, ah1, al1;
    {
      const float* ar = abase + (size_t)(p0 + l16) * Dd;
      float a0[8], a1[8];
      *(float4*)&a0[0] = *(const float4*)(ar + quad * 8);
      *(float4*)&a0[4] = *(const float4*)(ar + quad * 8 + 4);
      *(float4*)&a1[0] = *(const float4*)(ar + 32 + quad * 8);
      *(float4*)&a1[4] = *(const float4*)(ar + 32 + quad * 8 + 4);
      split8(a0, ah0, al0);
      split8(a1, ah1, al1);
    }
    const float4 tq = *(const float4*)(targets + b * Pp + p0 + quad * 4);

    float cc[2][4], av[2][4];
#pragma unroll
    for (int nt = 0; nt < 2; ++nt) {
      const int tl = wid * 32 + nt * 16 + l16;   // local t row in LDS
      const int bo = tl * 72 + quad * 8;
      const bf16x8 bh0 = *(const bf16x8*)&Bhs[bo];
      const bf16x8 bh1 = *(const bf16x8*)&Bhs[bo + 32];
      const bf16x8 bl0 = *(const bf16x8*)&Bls[bo];
      const bf16x8 bl1 = *(const bf16x8*)&Bls[bo + 32];
      f32x4 a = (f32x4)0.f;
      MFMA6(a)

      float sc[4];
      { const float e = tq.x - a[0]; sc[0] = -0.5f * e * e; }
      { const float e = tq.y - a[1]; sc[1] = -0.5f * e * e; }
      { const float e = tq.z - a[2]; sc[2] = -0.5f * e * e; }
      { const float e = tq.w - a[3]; sc[3] = -0.5f * e * e; }

      // quad-exclusive prefix of column sums (R11/R12-proven)
      const float colsum = (sc[0] + sc[1]) + (sc[2] + sc[3]);
      const float x1 = __shfl_xor(colsum, 16, 64);
      const float x2 = __shfl_xor(colsum, 32, 64);
      const float x3 = __shfl_xor(x1, 32, 64);
      const float pre = (quad == 0) ? 0.f
                      : (quad == 1) ? x1
                      : (quad == 2) ? (x2 + x3)
                                    : (x1 + x2 + x3);
      const float base = R[nt] + pre;
      cc[nt][0] = base;
      cc[nt][1] = base + sc[0];
      cc[nt][2] = cc[nt][1] + sc[1];
      cc[nt][3] = cc[nt][2] + sc[2];
#pragma unroll
      for (int r = 0; r < 4; ++r) av[nt][r] = a[r];

      R[nt] += ((colsum + x1) + (x2 + x3));    // inclusive through this sg
    }

    // batch softmax over this lane's 2 columns, per p-row r
    float mm[4], ss[4], vv[4];
#pragma unroll
    for (int r = 0; r < 4; ++r) {
      mm[r] = fmaxf(cc[0][r], cc[1][r]);
      const float e0 = __expf(cc[0][r] - mm[r]);
      const float e1 = __expf(cc[1][r] - mm[r]);
      ss[r] = e0 + e1;
      vv[r] = fmaf(e0, av[0][r], e1 * av[1][r]);
    }

    // l16 butterfly: exact max rounds, single rescale, plain-sum rounds
    float M[4];
#pragma unroll
    for (int r = 0; r < 4; ++r) M[r] = mm[r];
#pragma unroll
    for (int off = 1; off < 16; off <<= 1)
#pragma unroll
      for (int r = 0; r < 4; ++r) M[r] = fmaxf(M[r], __shfl_xor(M[r], off, 64));
#pragma unroll
    for (int r = 0; r < 4; ++r) {
      const float f = __expf(mm[r] - M[r]);    // ==1 at the argmax lane
      ss[r] *= f; vv[r] *= f;
    }
#pragma unroll
    for (int off = 1; off < 16; off <<= 1)
#pragma unroll
      for (int r = 0; r < 4; ++r) {
        ss[r] += __shfl_xor(ss[r], off, 64);
        vv[r] += __shfl_xor(vv[r], off, 64);
      }

    if (l16 == 0) {
#pragma unroll
      for (int r = 0; r < 4; ++r) {
        const int p = p0 + quad * 4 + r;
        trb[p * 128 + wstrip] = make_float4(M[r], ss[r], vv[r], 0.f);
      }
    }
  }
}

// ============== Phase 2: cross-strip merge (128 triples/(b,p)) ==============
// Lane pre-merges 2 triples (lane, lane+64), then the R6-proven 64-butterfly.
__global__ __launch_bounds__(256) void k_merge2(const float4* __restrict__ ws,
                                                float* __restrict__ out) {
  const int gt   = blockIdx.x * 256 + threadIdx.x;
  const int bp   = gt >> 6;
  const int lane = gt & 63;
  const float4 o0 = ws[(size_t)bp * 128 + lane];
  const float4 o1 = ws[(size_t)bp * 128 + 64 + lane];
  float M = fmaxf(o0.x, o1.x);
  const float g0 = __expf(o0.x - M), g1 = __expf(o1.x - M);
  float S = g0 * o0.y + g1 * o1.y;
  float V = g0 * o0.z + g1 * o1.z;
#pragma unroll
  for (int off = 1; off < 64; off <<= 1) {
    const float mo = __shfl_xor(M, off, 64);
    const float so = __shfl_xor(S, off, 64);
    const float vo = __shfl_xor(V, off, 64);
    const float mn = fmaxf(M, mo);
    const float f0 = __expf(M - mn), f1 = __expf(mo - mn);
    S = S * f0 + so * f1;
    V = V * f0 + vo * f1;
    M = mn;
  }
  if (lane == 0) out[bp] = V / S;
}

// ============== Fallback (tiny ws): fused R1 structure + merge ==============
__global__ __launch_bounds__(256) void k_scan_fused(const float* __restrict__ data,
                                                    const float* __restrict__ targets,
                                                    const float* __restrict__ task_pool,
                                                    float4* __restrict__ ws) {
  const int b     = blockIdx.x >> 4;
  const int wid   = threadIdx.x >> 6;
  const int lane  = threadIdx.x & 63;
  const int chunk = ((blockIdx.x & 15) << 2) | wid;
  const int t     = (chunk << 6) | lane;
  float w[Dd];
#pragma unroll
  for (int d = 0; d < Dd; d += 4) {
    const float4 r = *(const float4*)(task_pool + (size_t)t * Dd + d);
    w[d] = r.x; w[d + 1] = r.y; w[d + 2] = r.z; w[d + 3] = r.w;
  }
  const float* drow = data + (size_t)b * (Pp * Dd);
  const float* tgt  = targets + b * Pp;
  float4* wsb       = ws + (size_t)b * (Pp * 64);
  float c = 0.f;
  for (int p = 0; p < Pp; ++p) {
    float a0 = 0.f, a1 = 0.f, a2 = 0.f, a3 = 0.f;
    const float* r = drow + p * Dd;
#pragma unroll
    for (int d = 0; d < Dd; d += 4) {
      a0 = fmaf(r[d], w[d], a0);         a1 = fmaf(r[d + 1], w[d + 1], a1);
      a2 = fmaf(r[d + 2], w[d + 2], a2); a3 = fmaf(r[d + 3], w[d + 3], a3);
    }
    const float pred = (a0 + a1) + (a2 + a3);
    float m = c;
#pragma unroll
    for (int off = 32; off; off >>= 1) m = fmaxf(m, __shfl_xor(m, off, 64));
    const float e = __expf(c - m);
    float s = e, v = e * pred;
#pragma unroll
    for (int off = 32; off; off >>= 1) {
      s += __shfl_xor(s, off, 64);
      v += __shfl_xor(v, off, 64);
    }
    if (lane == 0) wsb[p * 64 + chunk] = make_float4(m, s, v, 0.f);
    const float err = tgt[p] - pred;
    c = fmaf(-0.5f * err, err, c);
  }
}

__global__ __launch_bounds__(256) void k_merge(const float4* __restrict__ ws,
                                               float* __restrict__ out) {
  const int gt   = blockIdx.x * 256 + threadIdx.x;
  const int bp   = gt >> 6;
  const int lane = gt & 63;
  const float4 o = ws[(size_t)bp * 64 + lane];
  const float m = o.x, s = o.y, v = o.z;
  float M = m;
#pragma unroll
  for (int off = 32; off; off >>= 1) M = fmaxf(M, __shfl_xor(M, off, 64));
  const float f = __expf(m - M);
  float S = f * s, V = f * v;
#pragma unroll
  for (int off = 32; off; off >>= 1) {
    S += __shfl_xor(S, off, 64);
    V += __shfl_xor(V, off, 64);
  }
  if (lane == 0) out[bp] = V / S;
}

extern "C" void kernel_launch(void* const* d_in, const int* in_sizes, int n_in,
                              void* d_out, int out_size, void* d_ws, size_t ws_size,
                              hipStream_t stream) {
  const float* data      = (const float*)d_in[0];
  const float* targets   = (const float*)d_in[1];
  const float* task_pool = (const float*)d_in[2];
  float* out = (float*)d_out;

  if (ws_size >= TRIP2_BYTES) {
    float4* trips = (float4*)d_ws;
    k_main2<<<dim3(Bb * 32), dim3(256), 0, stream>>>(data, task_pool, targets, trips);
    k_merge2<<<dim3((Bb * Pp * 64) / 256), dim3(256), 0, stream>>>(trips, out);
  } else {
    float4* triples = (float4*)d_ws;   // 8.4 MB
    k_scan_fused<<<dim3(512), dim3(256), 0, stream>>>(data, targets, task_pool, triples);
    k_merge<<<dim3((Bb * Pp * 64) / 256), dim3(256), 0, stream>>>(triples, out);
  }
}

// Round 14
// 108.869 us; speedup vs baseline: 1.0454x; 1.0454x over previous
//
#include <hip/hip_runtime.h>
#include <hip/hip_bf16.h>
#include <math.h>

// Problem constants (reference: B=32, P=256, D=64, T=4096, SCALE=1)
#define Bb 32
#define Pp 256
#define Dd 64
#define Tt 4096

typedef unsigned short ushort_t;
typedef __attribute__((ext_vector_type(8))) short bf16x8;   // 8 bf16 = 4 VGPRs
typedef __attribute__((ext_vector_type(4))) float f32x4;

#define TRIP2_BYTES ((size_t)Bb * Pp * 128 * 16)  // 16,777,216 (128 strips)
#define A_BF_BYTES  ((size_t)Bb * Pp * Dd * 2)    //  1,048,576 (each of hi/lo)
#define B_BF_BYTES  ((size_t)Tt * Dd * 2)         //    524,288 (each of hi/lo)
#define WS_NEED     (TRIP2_BYTES + 2 * A_BF_BYTES + 2 * B_BF_BYTES)

#define MFMA6(a)                                                     \
  a = __builtin_amdgcn_mfma_f32_16x16x32_bf16(ah0, bh0, a, 0, 0, 0); \
  a = __builtin_amdgcn_mfma_f32_16x16x32_bf16(ah1, bh1, a, 0, 0, 0); \
  a = __builtin_amdgcn_mfma_f32_16x16x32_bf16(ah0, bl0, a, 0, 0, 0); \
  a = __builtin_amdgcn_mfma_f32_16x16x32_bf16(al0, bh0, a, 0, 0, 0); \
  a = __builtin_amdgcn_mfma_f32_16x16x32_bf16(ah1, bl1, a, 0, 0, 0); \
  a = __builtin_amdgcn_mfma_f32_16x16x32_bf16(al1, bh1, a, 0, 0, 0);

// DPP row_ror:N within 16-lane rows — VALU pipe, replaces ds_swizzle for the
// l16 reductions (R13 post-mortem: butterfly shuffles saturated the LDS pipe).
template <int CTRL>
__device__ __forceinline__ float dpp_rot(float x) {
  return __int_as_float(__builtin_amdgcn_update_dpp(
      0, __float_as_int(x), CTRL, 0xF, 0xF, true));
}
// rotation schedule {8,4,2,1} aggregates all 16 lanes of a row (valid for
// commutative ops; every lane ends with the full result).
#define ROW_ROR_8 0x128
#define ROW_ROR_4 0x124
#define ROW_ROR_2 0x122
#define ROW_ROR_1 0x121

// =============== Phase 0: split-bf16 conversion of A and B ==================
// x = hi(bf16,RNE) + lo(bf16); dropped al*bl term ~2^-17 rel; pred err ~5e-4.
// Launches are free (R13 finding: ~50us overhead is FIXED, not per-launch).
__global__ __launch_bounds__(256) void k_conv(const float* __restrict__ data,
                                              const float* __restrict__ Wt,
                                              ushort_t* __restrict__ Ah, ushort_t* __restrict__ Al,
                                              ushort_t* __restrict__ Bh, ushort_t* __restrict__ Bl) {
  const int i  = blockIdx.x * 256 + threadIdx.x;
  const int NA = Bb * Pp * Dd;    // 524288
  const float x = (i < NA) ? data[i] : Wt[i - NA];
  const __hip_bfloat16 h = __float2bfloat16(x);
  const float hf = __bfloat162float(h);
  const __hip_bfloat16 l = __float2bfloat16(x - hf);
  if (i < NA) { Ah[i] = *(const ushort_t*)&h; Al[i] = *(const ushort_t*)&l; }
  else        { const int j = i - NA;
                Bh[j] = *(const ushort_t*)&h; Bl[j] = *(const ushort_t*)&l; }
}

// ==================== Phase 1: one-pass fused prefix-softmax ================
// R13 post-mortem: LDS-pipe-throughput bound (B-frag ds_reads re-issued every
// sg + 54 ds_swizzle butterfly = ~44us of LDS-pipe occupancy). R14:
//   (a) B-frags hoisted to REGISTERS (8 bf16x8 = 32 VGPR/wave, loaded once;
//       LDS deleted entirely -> ds_reads 128/wave -> 8/wave).
//   (b) l16 butterfly on DPP row_ror (VALU pipe) instead of ds_swizzle.
//   (c) A/B preconverted in k_conv (sg loop has zero split VALU).
// Grid 1024 = (b, 128-t strip), 4 waves/block, 0 LDS -> 4 blocks/CU.
// Math per sg (R12-proven): quad-exclusive prefix via 3 shuffles, in-register
// column prefix R[nt], batch softmax, l16 merge, factored-triple store.
// NaN-safety (R3): per-wave M is the exact max of that wave's cc -> argmax
// term contributes exp(0)=1 -> S>=1; factored exp(m-M) merges are exact.
__global__ __launch_bounds__(256, 4) void k_main3(const ushort_t* __restrict__ Ah,
                                                  const ushort_t* __restrict__ Al,
                                                  const ushort_t* __restrict__ Bh,
                                                  const ushort_t* __restrict__ Bl,
                                                  const float* __restrict__ targets,
                                                  float4* __restrict__ triples) {
  const int tid  = threadIdx.x;
  const int wid  = tid >> 6;
  const int lane = tid & 63;
  const int quad = lane >> 4;
  const int l16  = lane & 15;
  const int b     = blockIdx.x >> 5;
  const int strip = blockIdx.x & 31;
  const int t0    = strip * 128;

  // ---- B fragments for this wave's 32 t-columns: load ONCE into registers
  bf16x8 Bf[2][4];   // [nt][bh0,bh1,bl0,bl1]
#pragma unroll
  for (int nt = 0; nt < 2; ++nt) {
    const size_t brow = (size_t)(t0 + wid * 32 + nt * 16 + l16) * Dd + quad * 8;
    Bf[nt][0] = *(const bf16x8*)(Bh + brow);
    Bf[nt][1] = *(const bf16x8*)(Bh + brow + 32);
    Bf[nt][2] = *(const bf16x8*)(Bl + brow);
    Bf[nt][3] = *(const bf16x8*)(Bl + brow + 32);
  }

  const ushort_t* __restrict__ ahb = Ah + (size_t)b * Pp * Dd;
  const ushort_t* __restrict__ alb = Al + (size_t)b * Pp * Dd;
  float4* __restrict__ trb = triples + (size_t)b * Pp * 128;
  const int wstrip = strip * 4 + wid;      // 0..127

  float R[2];                              // per-column running prefix
  R[0] = 0.f; R[1] = 0.f;

#pragma unroll 1
  for (int sg = 0; sg < 16; ++sg) {
    const int p0 = sg * 16;
    const size_t aoff = (size_t)(p0 + l16) * Dd + quad * 8;
    const bf16x8 ah0 = *(const bf16x8*)(ahb + aoff);
    const bf16x8 ah1 = *(const bf16x8*)(ahb + aoff + 32);
    const bf16x8 al0 = *(const bf16x8*)(alb + aoff);
    const bf16x8 al1 = *(const bf16x8*)(alb + aoff + 32);
    const float4 tq = *(const float4*)(targets + b * Pp + p0 + quad * 4);

    float cc[2][4], av[2][4];
#pragma unroll
    for (int nt = 0; nt < 2; ++nt) {
      const bf16x8 bh0 = Bf[nt][0], bh1 = Bf[nt][1];
      const bf16x8 bl0 = Bf[nt][2], bl1 = Bf[nt][3];
      f32x4 a = (f32x4)0.f;
      MFMA6(a)

      float sc[4];
      { const float e = tq.x - a[0]; sc[0] = -0.5f * e * e; }
      { const float e = tq.y - a[1]; sc[1] = -0.5f * e * e; }
      { const float e = tq.z - a[2]; sc[2] = -0.5f * e * e; }
      { const float e = tq.w - a[3]; sc[3] = -0.5f * e * e; }

      // quad-exclusive prefix of column sums (cross-quad -> ds_swizzle, cheap)
      const float colsum = (sc[0] + sc[1]) + (sc[2] + sc[3]);
      const float x1 = __shfl_xor(colsum, 16, 64);
      const float x2 = __shfl_xor(colsum, 32, 64);
      const float x3 = __shfl_xor(x1, 32, 64);
      const float pre = (quad == 0) ? 0.f
                      : (quad == 1) ? x1
                      : (quad == 2) ? (x2 + x3)
                                    : (x1 + x2 + x3);
      const float base = R[nt] + pre;
      cc[nt][0] = base;
      cc[nt][1] = base + sc[0];
      cc[nt][2] = cc[nt][1] + sc[1];
      cc[nt][3] = cc[nt][2] + sc[2];
#pragma unroll
      for (int r = 0; r < 4; ++r) av[nt][r] = a[r];

      R[nt] += ((colsum + x1) + (x2 + x3));    // inclusive through this sg
    }

    // batch softmax over this lane's 2 columns, per p-row r
    float mm[4], ss[4], vv[4];
#pragma unroll
    for (int r = 0; r < 4; ++r) {
      mm[r] = fmaxf(cc[0][r], cc[1][r]);
      const float e0 = __expf(cc[0][r] - mm[r]);
      const float e1 = __expf(cc[1][r] - mm[r]);
      ss[r] = e0 + e1;
      vv[r] = fmaf(e0, av[0][r], e1 * av[1][r]);
    }

    // l16 merge on DPP (VALU pipe): max rounds -> single rescale -> sum rounds
    float M[4];
#pragma unroll
    for (int r = 0; r < 4; ++r) {
      float m = mm[r];
      m = fmaxf(m, dpp_rot<ROW_ROR_8>(m));
      m = fmaxf(m, dpp_rot<ROW_ROR_4>(m));
      m = fmaxf(m, dpp_rot<ROW_ROR_2>(m));
      m = fmaxf(m, dpp_rot<ROW_ROR_1>(m));
      M[r] = m;
    }
#pragma unroll
    for (int r = 0; r < 4; ++r) {
      const float f = __expf(mm[r] - M[r]);    // ==1 at the argmax lane
      float s = ss[r] * f, v = vv[r] * f;
      s += dpp_rot<ROW_ROR_8>(s);  v += dpp_rot<ROW_ROR_8>(v);
      s += dpp_rot<ROW_ROR_4>(s);  v += dpp_rot<ROW_ROR_4>(v);
      s += dpp_rot<ROW_ROR_2>(s);  v += dpp_rot<ROW_ROR_2>(v);
      s += dpp_rot<ROW_ROR_1>(s);  v += dpp_rot<ROW_ROR_1>(v);
      ss[r] = s; vv[r] = v;
    }

    if (l16 == 0) {
#pragma unroll
      for (int r = 0; r < 4; ++r) {
        const int p = p0 + quad * 4 + r;
        trb[p * 128 + wstrip] = make_float4(M[r], ss[r], vv[r], 0.f);
      }
    }
  }
}

// ============== Phase 2: cross-strip merge (128 triples/(b,p)) ==============
// Lane pre-merges 2 triples (lane, lane+64), then the R6-proven 64-butterfly.
__global__ __launch_bounds__(256) void k_merge2(const float4* __restrict__ ws,
                                                float* __restrict__ out) {
  const int gt   = blockIdx.x * 256 + threadIdx.x;
  const int bp   = gt >> 6;
  const int lane = gt & 63;
  const float4 o0 = ws[(size_t)bp * 128 + lane];
  const float4 o1 = ws[(size_t)bp * 128 + 64 + lane];
  float M = fmaxf(o0.x, o1.x);
  const float g0 = __expf(o0.x - M), g1 = __expf(o1.x - M);
  float S = g0 * o0.y + g1 * o1.y;
  float V = g0 * o0.z + g1 * o1.z;
#pragma unroll
  for (int off = 1; off < 64; off <<= 1) {
    const float mo = __shfl_xor(M, off, 64);
    const float so = __shfl_xor(S, off, 64);
    const float vo = __shfl_xor(V, off, 64);
    const float mn = fmaxf(M, mo);
    const float f0 = __expf(M - mn), f1 = __expf(mo - mn);
    S = S * f0 + so * f1;
    V = V * f0 + vo * f1;
    M = mn;
  }
  if (lane == 0) out[bp] = V / S;
}

// ============== Fallback (tiny ws): fused R1 structure + merge ==============
__global__ __launch_bounds__(256) void k_scan_fused(const float* __restrict__ data,
                                                    const float* __restrict__ targets,
                                                    const float* __restrict__ task_pool,
                                                    float4* __restrict__ ws) {
  const int b     = blockIdx.x >> 4;
  const int wid   = threadIdx.x >> 6;
  const int lane  = threadIdx.x & 63;
  const int chunk = ((blockIdx.x & 15) << 2) | wid;
  const int t     = (chunk << 6) | lane;
  float w[Dd];
#pragma unroll
  for (int d = 0; d < Dd; d += 4) {
    const float4 r = *(const float4*)(task_pool + (size_t)t * Dd + d);
    w[d] = r.x; w[d + 1] = r.y; w[d + 2] = r.z; w[d + 3] = r.w;
  }
  const float* drow = data + (size_t)b * (Pp * Dd);
  const float* tgt  = targets + b * Pp;
  float4* wsb       = ws + (size_t)b * (Pp * 64);
  float c = 0.f;
  for (int p = 0; p < Pp; ++p) {
    float a0 = 0.f, a1 = 0.f, a2 = 0.f, a3 = 0.f;
    const float* r = drow + p * Dd;
#pragma unroll
    for (int d = 0; d < Dd; d += 4) {
      a0 = fmaf(r[d], w[d], a0);         a1 = fmaf(r[d + 1], w[d + 1], a1);
      a2 = fmaf(r[d + 2], w[d + 2], a2); a3 = fmaf(r[d + 3], w[d + 3], a3);
    }
    const float pred = (a0 + a1) + (a2 + a3);
    float m = c;
#pragma unroll
    for (int off = 32; off; off >>= 1) m = fmaxf(m, __shfl_xor(m, off, 64));
    const float e = __expf(c - m);
    float s = e, v = e * pred;
#pragma unroll
    for (int off = 32; off; off >>= 1) {
      s += __shfl_xor(s, off, 64);
      v += __shfl_xor(v, off, 64);
    }
    if (lane == 0) wsb[p * 64 + chunk] = make_float4(m, s, v, 0.f);
    const float err = tgt[p] - pred;
    c = fmaf(-0.5f * err, err, c);
  }
}

__global__ __launch_bounds__(256) void k_merge(const float4* __restrict__ ws,
                                               float* __restrict__ out) {
  const int gt   = blockIdx.x * 256 + threadIdx.x;
  const int bp   = gt >> 6;
  const int lane = gt & 63;
  const float4 o = ws[(size_t)bp * 64 + lane];
  const float m = o.x, s = o.y, v = o.z;
  float M = m;
#pragma unroll
  for (int off = 32; off; off >>= 1) M = fmaxf(M, __shfl_xor(M, off, 64));
  const float f = __expf(m - M);
  float S = f * s, V = f * v;
#pragma unroll
  for (int off = 32; off; off >>= 1) {
    S += __shfl_xor(S, off, 64);
    V += __shfl_xor(V, off, 64);
  }
  if (lane == 0) out[bp] = V / S;
}

extern "C" void kernel_launch(void* const* d_in, const int* in_sizes, int n_in,
                              void* d_out, int out_size, void* d_ws, size_t ws_size,
                              hipStream_t stream) {
  const float* data      = (const float*)d_in[0];
  const float* targets   = (const float*)d_in[1];
  const float* task_pool = (const float*)d_in[2];
  float* out = (float*)d_out;

  if (ws_size >= WS_NEED) {
    float4*   trips = (float4*)d_ws;
    char*     cb    = (char*)d_ws + TRIP2_BYTES;
    ushort_t* Ah    = (ushort_t*)cb;
    ushort_t* Al    = (ushort_t*)(cb + A_BF_BYTES);
    ushort_t* Bh    = (ushort_t*)(cb + 2 * A_BF_BYTES);
    ushort_t* Bl    = (ushort_t*)(cb + 2 * A_BF_BYTES + B_BF_BYTES);
    k_conv  <<<dim3((Bb * Pp * Dd + Tt * Dd) / 256), dim3(256), 0, stream>>>(
        data, task_pool, Ah, Al, Bh, Bl);
    k_main3 <<<dim3(Bb * 32), dim3(256), 0, stream>>>(Ah, Al, Bh, Bl, targets, trips);
    k_merge2<<<dim3((Bb * Pp * 64) / 256), dim3(256), 0, stream>>>(trips, out);
  } else {
    float4* triples = (float4*)d_ws;   // 8.4 MB
    k_scan_fused<<<dim3(512), dim3(256), 0, stream>>>(data, targets, task_pool, triples);
    k_merge<<<dim3((Bb * Pp * 64) / 256), dim3(256), 0, stream>>>(triples, out);
  }
}